// Round 2
// baseline (530.685 us; speedup 1.0000x reference)
//
#include <hip/hip_runtime.h>
#include <math.h>

#define NCH 48
#define NB 16
#define PLANE 16384
#define NPLANES 768

// d_ws float layout
#define WS_PSUM  0      // 768 partial sums (per b,c plane)
#define WS_PSQ   768    // 768 partial sumsq
#define WS_SCALE 1536   // 48
#define WS_SHIFT 1584   // 48
#define WS_TAB   1632   // [src 4][tgt 4][6 coefs]
#define WS_CONST 1728   // [4]

// ---------------- stage A: per-plane partial sums ----------------
__global__ __launch_bounds__(256) void stats_kernel(const float* __restrict__ x,
                                                    float* __restrict__ ws) {
  int p = blockIdx.x;      // plane = b*48+c
  int t = threadIdx.x;
  const float4* x4 = (const float4*)x + (size_t)p * 4096;
  float s = 0.f, q = 0.f;
  #pragma unroll
  for (int k = 0; k < 16; ++k) {          // 256 thr * 16 = 4096 float4 = full plane
    float4 v = x4[k * 256 + t];
    s += v.x + v.y + v.z + v.w;
    q += v.x * v.x + v.y * v.y + v.z * v.z + v.w * v.w;
  }
  #pragma unroll
  for (int off = 32; off > 0; off >>= 1) {
    s += __shfl_xor(s, off, 64);
    q += __shfl_xor(q, off, 64);
  }
  __shared__ float red[8];
  int wid = t >> 6, lane = t & 63;
  if (lane == 0) { red[wid] = s; red[4 + wid] = q; }
  __syncthreads();
  if (t == 0) {
    ws[WS_PSUM + p] = red[0] + red[1] + red[2] + red[3];
    ws[WS_PSQ  + p] = red[4] + red[5] + red[6] + red[7];
  }
}

// ---------------- stage B: finalize BN params + weight table ----------------
__global__ void prep_kernel(const float* __restrict__ gamma, const float* __restrict__ beta,
                            const float* __restrict__ alphas, float* __restrict__ ws) {
  int t = threadIdx.x;
  if (t < NCH) {
    float s = 0.f, q = 0.f;
    for (int b = 0; b < NB; ++b) {
      s += ws[WS_PSUM + b * NCH + t];
      q += ws[WS_PSQ  + b * NCH + t];
    }
    const float inv = 1.0f / ((float)NB * PLANE);
    float mean = s * inv;
    float var  = q * inv - mean * mean;
    float sc = gamma[t] * rsqrtf(var + 1e-5f);
    ws[WS_SCALE + t] = sc;
    ws[WS_SHIFT + t] = beta[t] - mean * sc;
  }
  if (t == 0) {
    float w[14][7];
    for (int r = 0; r < 14; ++r) {
      float m = -1e30f;
      for (int k = 0; k < 7; ++k) m = fmaxf(m, alphas[r * 7 + k]);
      float sum = 0.f;
      for (int k = 0; k < 7; ++k) { float e = expf(alphas[r * 7 + k] - m); w[r][k] = e; sum += e; }
      float is = 1.0f / sum;
      for (int k = 0; k < 7; ++k) w[r][k] *= is;
    }
    for (int i = 0; i < 96; ++i) ws[WS_TAB + i] = 0.f;
    for (int i = 0; i < 4;  ++i) ws[WS_CONST + i] = 0.f;
    // weight-row -> (source p, target tg): s2=rows{0,1}; s3={2,3 | s2:4};
    // s4={5,6 | s2:7 | s3:8}; s5={9,10 | s2:11 | s3:12 | s4:13}
    const int map[14][2] = {
      {0,0},{0,0},
      {0,1},{0,1},{1,1},
      {0,2},{0,2},{1,2},{2,2},
      {0,3},{0,3},{1,3},{2,3},{3,3}
    };
    for (int r = 0; r < 14; ++r) {
      int p = map[r][0], tg = map[r][1];
      float* cf = ws + WS_TAB + (p * 4 + tg) * 6;
      cf[0] += w[r][0] - w[r][2];       // identity  (w0*h - w2*h)
      cf[1] += w[r][1] * (1.0f / 9.0f); // blur (fold /9)
      cf[2] += w[r][3];                 // fliplr
      cf[3] += w[r][4];                 // flipud
      cf[4] += w[r][5];                 // roll(+4,+4)
      cf[5] += w[r][6];                 // rot90
      ws[WS_CONST + tg] += w[r][2];     // constant w2*1
    }
  }
}

// ---------------- main fused kernel ----------------
// LDS swizzle: float4-block index for (row i, block bj): bj ^= (i>>2)&7.
__device__ __forceinline__ int swb(int i, int bj) {
  return (i << 5) + (bj ^ ((i >> 2) & 7));
}
__device__ __forceinline__ float ldsw(const float* l, int i, int j) {
  int bj = j >> 2;
  return l[(i << 7) + (((bj ^ ((i >> 2) & 7)) << 2) | (j & 3))];
}

template<int T0>
__device__ __forceinline__ void gather_pass(const float4* l4, const float* l1,
    int oi, int oj, int ty, int tx, const float (&cf)[4][6], float (&acc)[4][16])
{
  // ---- identity + box blur (6 rows x 6 cols, reflect borders) ----
  int cLo = (tx == 0)  ? 1   : oj - 1;
  int cHi = (tx == 31) ? 126 : oj + 4;
  float hs[3][4];
  #pragma unroll
  for (int r = 0; r < 6; ++r) {
    int ri = oi - 1 + r;
    ri = (ri < 0) ? 1 : ((ri > 127) ? 126 : ri);
    float4 mid = l4[swb(ri, tx)];
    float lo = ldsw(l1, ri, cLo);
    float hi = ldsw(l1, ri, cHi);
    if (r >= 1 && r <= 4) {
      const int a = r - 1;
      #pragma unroll
      for (int t = T0; t < 4; ++t) {
        acc[t][a * 4 + 0] += cf[t][0] * mid.x;
        acc[t][a * 4 + 1] += cf[t][0] * mid.y;
        acc[t][a * 4 + 2] += cf[t][0] * mid.z;
        acc[t][a * 4 + 3] += cf[t][0] * mid.w;
      }
    }
    hs[r % 3][0] = lo    + mid.x + mid.y;
    hs[r % 3][1] = mid.x + mid.y + mid.z;
    hs[r % 3][2] = mid.y + mid.z + mid.w;
    hs[r % 3][3] = mid.z + mid.w + hi;
    if (r >= 2) {
      const int a = r - 2;
      #pragma unroll
      for (int bq = 0; bq < 4; ++bq) {
        float bb = hs[0][bq] + hs[1][bq] + hs[2][bq];
        #pragma unroll
        for (int t = T0; t < 4; ++t) acc[t][a * 4 + bq] += cf[t][1] * bb;
      }
    }
  }
  // ---- fliplr: out[i][j] = src[i][127-j] ----
  #pragma unroll
  for (int a = 0; a < 4; ++a) {
    float4 m = l4[swb(oi + a, 31 - tx)];
    #pragma unroll
    for (int t = T0; t < 4; ++t) {
      acc[t][a * 4 + 0] += cf[t][2] * m.w;
      acc[t][a * 4 + 1] += cf[t][2] * m.z;
      acc[t][a * 4 + 2] += cf[t][2] * m.y;
      acc[t][a * 4 + 3] += cf[t][2] * m.x;
    }
  }
  // ---- flipud: out[i][j] = src[127-i][j] ----
  #pragma unroll
  for (int a = 0; a < 4; ++a) {
    float4 m = l4[swb(127 - oi - a, tx)];
    #pragma unroll
    for (int t = T0; t < 4; ++t) {
      acc[t][a * 4 + 0] += cf[t][3] * m.x;
      acc[t][a * 4 + 1] += cf[t][3] * m.y;
      acc[t][a * 4 + 2] += cf[t][3] * m.z;
      acc[t][a * 4 + 3] += cf[t][3] * m.w;
    }
  }
  // ---- roll(+4,+4): out[i][j] = src[(i-4)&127][(j-4)&127] ----
  #pragma unroll
  for (int a = 0; a < 4; ++a) {
    float4 m = l4[swb((oi + a - 4) & 127, (tx + 31) & 31)];
    #pragma unroll
    for (int t = T0; t < 4; ++t) {
      acc[t][a * 4 + 0] += cf[t][4] * m.x;
      acc[t][a * 4 + 1] += cf[t][4] * m.y;
      acc[t][a * 4 + 2] += cf[t][4] * m.z;
      acc[t][a * 4 + 3] += cf[t][4] * m.w;
    }
  }
  // ---- rot90 (k=1): out[i][j] = src[j][127-i] ----
  #pragma unroll
  for (int rb = 0; rb < 4; ++rb) {
    float4 m = l4[swb(oj + rb, 31 - ty)];
    // word w of block (31-ty) is col 124-4ty+w = 127-oi-a -> a = 3-w
    #pragma unroll
    for (int t = T0; t < 4; ++t) {
      acc[t][0 * 4 + rb] += cf[t][5] * m.w;
      acc[t][1 * 4 + rb] += cf[t][5] * m.z;
      acc[t][2 * 4 + rb] += cf[t][5] * m.y;
      acc[t][3 * 4 + rb] += cf[t][5] * m.x;
    }
  }
}

template<int P, int T0>
__device__ __forceinline__ void do_pass(const float* __restrict__ wsf, const float4* l4,
    const float* l1, int oi, int oj, int ty, int tx, float (&acc)[4][16])
{
  float cf[4][6];
  #pragma unroll
  for (int t = T0; t < 4; ++t) {
    #pragma unroll
    for (int k = 0; k < 6; ++k) cf[t][k] = wsf[WS_TAB + (P * 4 + t) * 6 + k];
  }
  gather_pass<T0>(l4, l1, oi, oj, ty, tx, cf, acc);
}

__global__ __launch_bounds__(1024) void main_kernel(const float* __restrict__ x,
    const float* __restrict__ wsf, float* __restrict__ out)
{
  __shared__ float lds[PLANE];   // 64 KB: one 128x128 plane, swizzled
  float4* l4 = (float4*)lds;
  int bx = blockIdx.x;
  int b = bx / NCH, c = bx % NCH;
  int tid = threadIdx.x;
  int ty = tid >> 5, tx = tid & 31;
  int oi = ty << 2, oj = tx << 2;

  // stage s = BN(x) into LDS
  float sc = wsf[WS_SCALE + c], sh = wsf[WS_SHIFT + c];
  const float4* x4 = (const float4*)x + (size_t)bx * 4096;
  #pragma unroll
  for (int r = 0; r < 4; ++r) {
    float4 v = x4[(oi + r) * 32 + tx];
    float4 sv;
    sv.x = v.x * sc + sh; sv.y = v.y * sc + sh;
    sv.z = v.z * sc + sh; sv.w = v.w * sc + sh;
    l4[swb(oi + r, tx)] = sv;
  }

  float acc[4][16];
  #pragma unroll
  for (int t = 0; t < 4; ++t) {
    float cst = wsf[WS_CONST + t];
    #pragma unroll
    for (int k = 0; k < 16; ++k) acc[t][k] = cst;
  }
  __syncthreads();

  float4* out4 = (float4*)out;
  const size_t pbase = (size_t)b * 192 + c;

  // pass 1: src = s, targets s2..s5
  do_pass<0, 0>(wsf, l4, lds, oi, oj, ty, tx, acc);
  #pragma unroll
  for (int r = 0; r < 4; ++r) {
    float4 v; v.x = acc[0][r*4+0]; v.y = acc[0][r*4+1]; v.z = acc[0][r*4+2]; v.w = acc[0][r*4+3];
    out4[(pbase + 0 * NCH) * 4096 + (oi + r) * 32 + tx] = v;
  }
  __syncthreads();
  #pragma unroll
  for (int r = 0; r < 4; ++r) {
    float4 v; v.x = acc[0][r*4+0]; v.y = acc[0][r*4+1]; v.z = acc[0][r*4+2]; v.w = acc[0][r*4+3];
    l4[swb(oi + r, tx)] = v;
  }
  __syncthreads();

  // pass 2: src = s2, targets s3..s5
  do_pass<1, 1>(wsf, l4, lds, oi, oj, ty, tx, acc);
  #pragma unroll
  for (int r = 0; r < 4; ++r) {
    float4 v; v.x = acc[1][r*4+0]; v.y = acc[1][r*4+1]; v.z = acc[1][r*4+2]; v.w = acc[1][r*4+3];
    out4[(pbase + 1 * NCH) * 4096 + (oi + r) * 32 + tx] = v;
  }
  __syncthreads();
  #pragma unroll
  for (int r = 0; r < 4; ++r) {
    float4 v; v.x = acc[1][r*4+0]; v.y = acc[1][r*4+1]; v.z = acc[1][r*4+2]; v.w = acc[1][r*4+3];
    l4[swb(oi + r, tx)] = v;
  }
  __syncthreads();

  // pass 3: src = s3, targets s4..s5
  do_pass<2, 2>(wsf, l4, lds, oi, oj, ty, tx, acc);
  #pragma unroll
  for (int r = 0; r < 4; ++r) {
    float4 v; v.x = acc[2][r*4+0]; v.y = acc[2][r*4+1]; v.z = acc[2][r*4+2]; v.w = acc[2][r*4+3];
    out4[(pbase + 2 * NCH) * 4096 + (oi + r) * 32 + tx] = v;
  }
  __syncthreads();
  #pragma unroll
  for (int r = 0; r < 4; ++r) {
    float4 v; v.x = acc[2][r*4+0]; v.y = acc[2][r*4+1]; v.z = acc[2][r*4+2]; v.w = acc[2][r*4+3];
    l4[swb(oi + r, tx)] = v;
  }
  __syncthreads();

  // pass 4: src = s4, target s5
  do_pass<3, 3>(wsf, l4, lds, oi, oj, ty, tx, acc);
  #pragma unroll
  for (int r = 0; r < 4; ++r) {
    float4 v; v.x = acc[3][r*4+0]; v.y = acc[3][r*4+1]; v.z = acc[3][r*4+2]; v.w = acc[3][r*4+3];
    out4[(pbase + 3 * NCH) * 4096 + (oi + r) * 32 + tx] = v;
  }
}

extern "C" void kernel_launch(void* const* d_in, const int* in_sizes, int n_in,
                              void* d_out, int out_size, void* d_ws, size_t ws_size,
                              hipStream_t stream) {
  (void)in_sizes; (void)n_in; (void)out_size; (void)ws_size;
  const float* x     = (const float*)d_in[0];
  const float* gamma = (const float*)d_in[1];
  const float* beta  = (const float*)d_in[2];
  const float* a_red = (const float*)d_in[4];   // reference uses alphas_reduce
  float* ws  = (float*)d_ws;
  float* out = (float*)d_out;

  stats_kernel<<<NPLANES, 256, 0, stream>>>(x, ws);
  prep_kernel<<<1, 64, 0, stream>>>(gamma, beta, a_red, ws);
  main_kernel<<<NPLANES, 1024, 0, stream>>>(x, ws, out);
}

// Round 3
// 525.110 us; speedup vs baseline: 1.0106x; 1.0106x over previous
//
#include <hip/hip_runtime.h>
#include <math.h>

#define NCH 48
#define NB 16
#define PLANE 16384
#define NPLANES 768

// d_ws float layout
#define WS_PSUM  0      // 768 partial sums (per b,c plane)
#define WS_PSQ   768    // 768 partial sumsq
#define WS_SCALE 1536   // 48
#define WS_SHIFT 1584   // 48
#define WS_TAB   1632   // [src 4][tgt 4][6 coefs]
#define WS_CONST 1728   // [4]

// ---------------- stage A: per-plane partial sums ----------------
__global__ __launch_bounds__(256) void stats_kernel(const float* __restrict__ x,
                                                    float* __restrict__ ws) {
  int p = blockIdx.x;      // plane = b*48+c
  int t = threadIdx.x;
  const float4* x4 = (const float4*)x + (size_t)p * 4096;
  float s = 0.f, q = 0.f;
  #pragma unroll
  for (int k = 0; k < 16; ++k) {          // 256 thr * 16 = 4096 float4 = full plane
    float4 v = x4[k * 256 + t];
    s += v.x + v.y + v.z + v.w;
    q += v.x * v.x + v.y * v.y + v.z * v.z + v.w * v.w;
  }
  #pragma unroll
  for (int off = 32; off > 0; off >>= 1) {
    s += __shfl_xor(s, off, 64);
    q += __shfl_xor(q, off, 64);
  }
  __shared__ float red[8];
  int wid = t >> 6, lane = t & 63;
  if (lane == 0) { red[wid] = s; red[4 + wid] = q; }
  __syncthreads();
  if (t == 0) {
    ws[WS_PSUM + p] = red[0] + red[1] + red[2] + red[3];
    ws[WS_PSQ  + p] = red[4] + red[5] + red[6] + red[7];
  }
}

// ---------------- stage B: finalize BN params + weight table ----------------
__global__ void prep_kernel(const float* __restrict__ gamma, const float* __restrict__ beta,
                            const float* __restrict__ alphas, float* __restrict__ ws) {
  int t = threadIdx.x;
  if (t < NCH) {
    float s = 0.f, q = 0.f;
    for (int b = 0; b < NB; ++b) {
      s += ws[WS_PSUM + b * NCH + t];
      q += ws[WS_PSQ  + b * NCH + t];
    }
    const float inv = 1.0f / ((float)NB * PLANE);
    float mean = s * inv;
    float var  = q * inv - mean * mean;
    float sc = gamma[t] * rsqrtf(var + 1e-5f);
    ws[WS_SCALE + t] = sc;
    ws[WS_SHIFT + t] = beta[t] - mean * sc;
  }
  if (t == 0) {
    float w[14][7];
    for (int r = 0; r < 14; ++r) {
      float m = -1e30f;
      for (int k = 0; k < 7; ++k) m = fmaxf(m, alphas[r * 7 + k]);
      float sum = 0.f;
      for (int k = 0; k < 7; ++k) { float e = expf(alphas[r * 7 + k] - m); w[r][k] = e; sum += e; }
      float is = 1.0f / sum;
      for (int k = 0; k < 7; ++k) w[r][k] *= is;
    }
    for (int i = 0; i < 96; ++i) ws[WS_TAB + i] = 0.f;
    for (int i = 0; i < 4;  ++i) ws[WS_CONST + i] = 0.f;
    // weight-row -> (source p, target tg): s2=rows{0,1}; s3={2,3 | s2:4};
    // s4={5,6 | s2:7 | s3:8}; s5={9,10 | s2:11 | s3:12 | s4:13}
    const int map[14][2] = {
      {0,0},{0,0},
      {0,1},{0,1},{1,1},
      {0,2},{0,2},{1,2},{2,2},
      {0,3},{0,3},{1,3},{2,3},{3,3}
    };
    for (int r = 0; r < 14; ++r) {
      int p = map[r][0], tg = map[r][1];
      float* cf = ws + WS_TAB + (p * 4 + tg) * 6;
      cf[0] += w[r][0] - w[r][2];       // identity  (w0*h - w2*h)
      cf[1] += w[r][1] * (1.0f / 9.0f); // blur (fold /9)
      cf[2] += w[r][3];                 // fliplr
      cf[3] += w[r][4];                 // flipud
      cf[4] += w[r][5];                 // roll(+4,+4)
      cf[5] += w[r][6];                 // rot90
      ws[WS_CONST + tg] += w[r][2];     // constant w2*1
    }
  }
}

// ---------------- main fused kernel ----------------
// LDS swizzle: float4-block index for (row i, block bj): bj ^= (i>>2)&7.
__device__ __forceinline__ int swb(int i, int bj) {
  return (i << 5) + (bj ^ ((i >> 2) & 7));
}
__device__ __forceinline__ float ldsw(const float* l, int i, int j) {
  int bj = j >> 2;
  return l[(i << 7) + (((bj ^ ((i >> 2) & 7)) << 2) | (j & 3))];
}

template<int T0>
__device__ __forceinline__ void gather_pass(const float4* l4, const float* l1,
    int oi, int oj, int ty, int tx, const float (&cf)[4][6], float (&acc)[4][16])
{
  // ---- identity + box blur (6 rows x 6 cols, reflect borders) ----
  int cLo = (tx == 0)  ? 1   : oj - 1;
  int cHi = (tx == 31) ? 126 : oj + 4;
  float hs[3][4];
  #pragma unroll
  for (int r = 0; r < 6; ++r) {
    int ri = oi - 1 + r;
    ri = (ri < 0) ? 1 : ((ri > 127) ? 126 : ri);
    float4 mid = l4[swb(ri, tx)];
    float lo = ldsw(l1, ri, cLo);
    float hi = ldsw(l1, ri, cHi);
    if (r >= 1 && r <= 4) {
      const int a = r - 1;
      #pragma unroll
      for (int t = T0; t < 4; ++t) {
        acc[t][a * 4 + 0] += cf[t][0] * mid.x;
        acc[t][a * 4 + 1] += cf[t][0] * mid.y;
        acc[t][a * 4 + 2] += cf[t][0] * mid.z;
        acc[t][a * 4 + 3] += cf[t][0] * mid.w;
      }
    }
    hs[r % 3][0] = lo    + mid.x + mid.y;
    hs[r % 3][1] = mid.x + mid.y + mid.z;
    hs[r % 3][2] = mid.y + mid.z + mid.w;
    hs[r % 3][3] = mid.z + mid.w + hi;
    if (r >= 2) {
      const int a = r - 2;
      #pragma unroll
      for (int bq = 0; bq < 4; ++bq) {
        float bb = hs[0][bq] + hs[1][bq] + hs[2][bq];
        #pragma unroll
        for (int t = T0; t < 4; ++t) acc[t][a * 4 + bq] += cf[t][1] * bb;
      }
    }
  }
  // ---- fliplr: out[i][j] = src[i][127-j] ----
  #pragma unroll
  for (int a = 0; a < 4; ++a) {
    float4 m = l4[swb(oi + a, 31 - tx)];
    #pragma unroll
    for (int t = T0; t < 4; ++t) {
      acc[t][a * 4 + 0] += cf[t][2] * m.w;
      acc[t][a * 4 + 1] += cf[t][2] * m.z;
      acc[t][a * 4 + 2] += cf[t][2] * m.y;
      acc[t][a * 4 + 3] += cf[t][2] * m.x;
    }
  }
  // ---- flipud: out[i][j] = src[127-i][j] ----
  #pragma unroll
  for (int a = 0; a < 4; ++a) {
    float4 m = l4[swb(127 - oi - a, tx)];
    #pragma unroll
    for (int t = T0; t < 4; ++t) {
      acc[t][a * 4 + 0] += cf[t][3] * m.x;
      acc[t][a * 4 + 1] += cf[t][3] * m.y;
      acc[t][a * 4 + 2] += cf[t][3] * m.z;
      acc[t][a * 4 + 3] += cf[t][3] * m.w;
    }
  }
  // ---- roll(+4,+4): out[i][j] = src[(i-4)&127][(j-4)&127] ----
  #pragma unroll
  for (int a = 0; a < 4; ++a) {
    float4 m = l4[swb((oi + a - 4) & 127, (tx + 31) & 31)];
    #pragma unroll
    for (int t = T0; t < 4; ++t) {
      acc[t][a * 4 + 0] += cf[t][4] * m.x;
      acc[t][a * 4 + 1] += cf[t][4] * m.y;
      acc[t][a * 4 + 2] += cf[t][4] * m.z;
      acc[t][a * 4 + 3] += cf[t][4] * m.w;
    }
  }
  // ---- rot90 (k=1): out[i][j] = src[j][127-i] ----
  #pragma unroll
  for (int rb = 0; rb < 4; ++rb) {
    float4 m = l4[swb(oj + rb, 31 - ty)];
    // word w of block (31-ty) is col 124-4ty+w = 127-oi-a -> a = 3-w
    #pragma unroll
    for (int t = T0; t < 4; ++t) {
      acc[t][0 * 4 + rb] += cf[t][5] * m.w;
      acc[t][1 * 4 + rb] += cf[t][5] * m.z;
      acc[t][2 * 4 + rb] += cf[t][5] * m.y;
      acc[t][3 * 4 + rb] += cf[t][5] * m.x;
    }
  }
}

template<int P, int T0>
__device__ __forceinline__ void do_pass(const float* __restrict__ wsf, const float4* l4,
    const float* l1, int oi, int oj, int ty, int tx, float (&acc)[4][16])
{
  float cf[4][6];
  #pragma unroll
  for (int t = T0; t < 4; ++t) {
    #pragma unroll
    for (int k = 0; k < 6; ++k) cf[t][k] = wsf[WS_TAB + (P * 4 + t) * 6 + k];
  }
  gather_pass<T0>(l4, l1, oi, oj, ty, tx, cf, acc);
}

// launch_bounds(1024, 4): 16 waves/block = 4 waves/SIMD with one resident
// block. Without the 2nd arg the compiler capped VGPR at 64 -> acc[4][16]
// spilled to scratch (~1.4 GB HBM traffic, dur 504us). 4 waves/SIMD lifts
// the cap to 512 VGPR; we need ~150-200 -> zero spill.
__global__ __launch_bounds__(1024, 4) void main_kernel(const float* __restrict__ x,
    const float* __restrict__ wsf, float* __restrict__ out)
{
  __shared__ float lds[PLANE];   // 64 KB: one 128x128 plane, swizzled
  float4* l4 = (float4*)lds;
  int bx = blockIdx.x;
  int b = bx / NCH, c = bx % NCH;
  int tid = threadIdx.x;
  int ty = tid >> 5, tx = tid & 31;
  int oi = ty << 2, oj = tx << 2;

  // stage s = BN(x) into LDS
  float sc = wsf[WS_SCALE + c], sh = wsf[WS_SHIFT + c];
  const float4* x4 = (const float4*)x + (size_t)bx * 4096;
  #pragma unroll
  for (int r = 0; r < 4; ++r) {
    float4 v = x4[(oi + r) * 32 + tx];
    float4 sv;
    sv.x = v.x * sc + sh; sv.y = v.y * sc + sh;
    sv.z = v.z * sc + sh; sv.w = v.w * sc + sh;
    l4[swb(oi + r, tx)] = sv;
  }

  float acc[4][16];
  #pragma unroll
  for (int t = 0; t < 4; ++t) {
    float cst = wsf[WS_CONST + t];
    #pragma unroll
    for (int k = 0; k < 16; ++k) acc[t][k] = cst;
  }
  __syncthreads();

  float4* out4 = (float4*)out;
  const size_t pbase = (size_t)b * 192 + c;

  // pass 1: src = s, targets s2..s5
  do_pass<0, 0>(wsf, l4, lds, oi, oj, ty, tx, acc);
  #pragma unroll
  for (int r = 0; r < 4; ++r) {
    float4 v; v.x = acc[0][r*4+0]; v.y = acc[0][r*4+1]; v.z = acc[0][r*4+2]; v.w = acc[0][r*4+3];
    out4[(pbase + 0 * NCH) * 4096 + (oi + r) * 32 + tx] = v;
  }
  __syncthreads();
  #pragma unroll
  for (int r = 0; r < 4; ++r) {
    float4 v; v.x = acc[0][r*4+0]; v.y = acc[0][r*4+1]; v.z = acc[0][r*4+2]; v.w = acc[0][r*4+3];
    l4[swb(oi + r, tx)] = v;
  }
  __syncthreads();

  // pass 2: src = s2, targets s3..s5
  do_pass<1, 1>(wsf, l4, lds, oi, oj, ty, tx, acc);
  #pragma unroll
  for (int r = 0; r < 4; ++r) {
    float4 v; v.x = acc[1][r*4+0]; v.y = acc[1][r*4+1]; v.z = acc[1][r*4+2]; v.w = acc[1][r*4+3];
    out4[(pbase + 1 * NCH) * 4096 + (oi + r) * 32 + tx] = v;
  }
  __syncthreads();
  #pragma unroll
  for (int r = 0; r < 4; ++r) {
    float4 v; v.x = acc[1][r*4+0]; v.y = acc[1][r*4+1]; v.z = acc[1][r*4+2]; v.w = acc[1][r*4+3];
    l4[swb(oi + r, tx)] = v;
  }
  __syncthreads();

  // pass 3: src = s3, targets s4..s5
  do_pass<2, 2>(wsf, l4, lds, oi, oj, ty, tx, acc);
  #pragma unroll
  for (int r = 0; r < 4; ++r) {
    float4 v; v.x = acc[2][r*4+0]; v.y = acc[2][r*4+1]; v.z = acc[2][r*4+2]; v.w = acc[2][r*4+3];
    out4[(pbase + 2 * NCH) * 4096 + (oi + r) * 32 + tx] = v;
  }
  __syncthreads();
  #pragma unroll
  for (int r = 0; r < 4; ++r) {
    float4 v; v.x = acc[2][r*4+0]; v.y = acc[2][r*4+1]; v.z = acc[2][r*4+2]; v.w = acc[2][r*4+3];
    l4[swb(oi + r, tx)] = v;
  }
  __syncthreads();

  // pass 4: src = s4, target s5
  do_pass<3, 3>(wsf, l4, lds, oi, oj, ty, tx, acc);
  #pragma unroll
  for (int r = 0; r < 4; ++r) {
    float4 v; v.x = acc[3][r*4+0]; v.y = acc[3][r*4+1]; v.z = acc[3][r*4+2]; v.w = acc[3][r*4+3];
    out4[(pbase + 3 * NCH) * 4096 + (oi + r) * 32 + tx] = v;
  }
}

extern "C" void kernel_launch(void* const* d_in, const int* in_sizes, int n_in,
                              void* d_out, int out_size, void* d_ws, size_t ws_size,
                              hipStream_t stream) {
  (void)in_sizes; (void)n_in; (void)out_size; (void)ws_size;
  const float* x     = (const float*)d_in[0];
  const float* gamma = (const float*)d_in[1];
  const float* beta  = (const float*)d_in[2];
  const float* a_red = (const float*)d_in[4];   // reference uses alphas_reduce
  float* ws  = (float*)d_ws;
  float* out = (float*)d_out;

  stats_kernel<<<NPLANES, 256, 0, stream>>>(x, ws);
  prep_kernel<<<1, 64, 0, stream>>>(gamma, beta, a_red, ws);
  main_kernel<<<NPLANES, 1024, 0, stream>>>(x, ws, out);
}

// Round 4
// 506.776 us; speedup vs baseline: 1.0472x; 1.0362x over previous
//
#include <hip/hip_runtime.h>
#include <math.h>

#define NCH 48
#define NB 16
#define PLANE 16384
#define NPLANES 768

// d_ws float layout
#define WS_PSUM  0      // 768 partial sums (per b,c plane)
#define WS_PSQ   768    // 768 partial sumsq
#define WS_SCALE 1536   // 48
#define WS_SHIFT 1584   // 48
#define WS_TAB   1632   // [src 4][tgt 4][6 coefs]
#define WS_CONST 1728   // [4]

// ---------------- stage A: per-plane partial sums ----------------
__global__ __launch_bounds__(256) void stats_kernel(const float* __restrict__ x,
                                                    float* __restrict__ ws) {
  int p = blockIdx.x;      // plane = b*48+c
  int t = threadIdx.x;
  const float4* x4 = (const float4*)x + (size_t)p * 4096;
  float s = 0.f, q = 0.f;
  #pragma unroll
  for (int k = 0; k < 16; ++k) {          // 256 thr * 16 = 4096 float4 = full plane
    float4 v = x4[k * 256 + t];
    s += v.x + v.y + v.z + v.w;
    q += v.x * v.x + v.y * v.y + v.z * v.z + v.w * v.w;
  }
  #pragma unroll
  for (int off = 32; off > 0; off >>= 1) {
    s += __shfl_xor(s, off, 64);
    q += __shfl_xor(q, off, 64);
  }
  __shared__ float red[8];
  int wid = t >> 6, lane = t & 63;
  if (lane == 0) { red[wid] = s; red[4 + wid] = q; }
  __syncthreads();
  if (t == 0) {
    ws[WS_PSUM + p] = red[0] + red[1] + red[2] + red[3];
    ws[WS_PSQ  + p] = red[4] + red[5] + red[6] + red[7];
  }
}

// ---------------- stage B: finalize BN params + weight table ----------------
__global__ void prep_kernel(const float* __restrict__ gamma, const float* __restrict__ beta,
                            const float* __restrict__ alphas, float* __restrict__ ws) {
  int t = threadIdx.x;
  if (t < NCH) {
    float s = 0.f, q = 0.f;
    for (int b = 0; b < NB; ++b) {
      s += ws[WS_PSUM + b * NCH + t];
      q += ws[WS_PSQ  + b * NCH + t];
    }
    const float inv = 1.0f / ((float)NB * PLANE);
    float mean = s * inv;
    float var  = q * inv - mean * mean;
    float sc = gamma[t] * rsqrtf(var + 1e-5f);
    ws[WS_SCALE + t] = sc;
    ws[WS_SHIFT + t] = beta[t] - mean * sc;
  }
  if (t == 0) {
    float w[14][7];
    for (int r = 0; r < 14; ++r) {
      float m = -1e30f;
      for (int k = 0; k < 7; ++k) m = fmaxf(m, alphas[r * 7 + k]);
      float sum = 0.f;
      for (int k = 0; k < 7; ++k) { float e = expf(alphas[r * 7 + k] - m); w[r][k] = e; sum += e; }
      float is = 1.0f / sum;
      for (int k = 0; k < 7; ++k) w[r][k] *= is;
    }
    for (int i = 0; i < 96; ++i) ws[WS_TAB + i] = 0.f;
    for (int i = 0; i < 4;  ++i) ws[WS_CONST + i] = 0.f;
    // weight-row -> (source p, target tg): s2=rows{0,1}; s3={2,3 | s2:4};
    // s4={5,6 | s2:7 | s3:8}; s5={9,10 | s2:11 | s3:12 | s4:13}
    const int map[14][2] = {
      {0,0},{0,0},
      {0,1},{0,1},{1,1},
      {0,2},{0,2},{1,2},{2,2},
      {0,3},{0,3},{1,3},{2,3},{3,3}
    };
    for (int r = 0; r < 14; ++r) {
      int p = map[r][0], tg = map[r][1];
      float* cf = ws + WS_TAB + (p * 4 + tg) * 6;
      cf[0] += w[r][0] - w[r][2];       // identity  (w0*h - w2*h)
      cf[1] += w[r][1] * (1.0f / 9.0f); // blur (fold /9)
      cf[2] += w[r][3];                 // fliplr
      cf[3] += w[r][4];                 // flipud
      cf[4] += w[r][5];                 // roll(+4,+4)
      cf[5] += w[r][6];                 // rot90
      ws[WS_CONST + tg] += w[r][2];     // constant w2*1
    }
  }
}

// ---------------- main fused kernel ----------------
// LDS swizzle: float4-block index for (row i, block bj): bj ^= (i>>2)&7.
__device__ __forceinline__ int swb(int i, int bj) {
  return (i << 5) + (bj ^ ((i >> 2) & 7));
}
__device__ __forceinline__ float ldsw(const float* l, int i, int j) {
  int bj = j >> 2;
  return l[(i << 7) + (((bj ^ ((i >> 2) & 7)) << 2) | (j & 3))];
}

template<int T0>
__device__ __forceinline__ void gather_pass(const float4* l4, const float* l1,
    int oi, int oj, int ty, int tx, const float (&cf)[4][6], float (&acc)[4][16])
{
  // ---- identity + box blur (6 rows x 6 cols, reflect borders) ----
  int cLo = (tx == 0)  ? 1   : oj - 1;
  int cHi = (tx == 31) ? 126 : oj + 4;
  float hs[3][4];
  #pragma unroll
  for (int r = 0; r < 6; ++r) {
    int ri = oi - 1 + r;
    ri = (ri < 0) ? 1 : ((ri > 127) ? 126 : ri);
    float4 mid = l4[swb(ri, tx)];
    float lo = ldsw(l1, ri, cLo);
    float hi = ldsw(l1, ri, cHi);
    if (r >= 1 && r <= 4) {
      const int a = r - 1;
      #pragma unroll
      for (int t = T0; t < 4; ++t) {
        acc[t][a * 4 + 0] += cf[t][0] * mid.x;
        acc[t][a * 4 + 1] += cf[t][0] * mid.y;
        acc[t][a * 4 + 2] += cf[t][0] * mid.z;
        acc[t][a * 4 + 3] += cf[t][0] * mid.w;
      }
    }
    hs[r % 3][0] = lo    + mid.x + mid.y;
    hs[r % 3][1] = mid.x + mid.y + mid.z;
    hs[r % 3][2] = mid.y + mid.z + mid.w;
    hs[r % 3][3] = mid.z + mid.w + hi;
    if (r >= 2) {
      const int a = r - 2;
      #pragma unroll
      for (int bq = 0; bq < 4; ++bq) {
        float bb = hs[0][bq] + hs[1][bq] + hs[2][bq];
        #pragma unroll
        for (int t = T0; t < 4; ++t) acc[t][a * 4 + bq] += cf[t][1] * bb;
      }
    }
  }
  // ---- fliplr: out[i][j] = src[i][127-j] ----
  #pragma unroll
  for (int a = 0; a < 4; ++a) {
    float4 m = l4[swb(oi + a, 31 - tx)];
    #pragma unroll
    for (int t = T0; t < 4; ++t) {
      acc[t][a * 4 + 0] += cf[t][2] * m.w;
      acc[t][a * 4 + 1] += cf[t][2] * m.z;
      acc[t][a * 4 + 2] += cf[t][2] * m.y;
      acc[t][a * 4 + 3] += cf[t][2] * m.x;
    }
  }
  // ---- flipud: out[i][j] = src[127-i][j] ----
  #pragma unroll
  for (int a = 0; a < 4; ++a) {
    float4 m = l4[swb(127 - oi - a, tx)];
    #pragma unroll
    for (int t = T0; t < 4; ++t) {
      acc[t][a * 4 + 0] += cf[t][3] * m.x;
      acc[t][a * 4 + 1] += cf[t][3] * m.y;
      acc[t][a * 4 + 2] += cf[t][3] * m.z;
      acc[t][a * 4 + 3] += cf[t][3] * m.w;
    }
  }
  // ---- roll(+4,+4): out[i][j] = src[(i-4)&127][(j-4)&127] ----
  #pragma unroll
  for (int a = 0; a < 4; ++a) {
    float4 m = l4[swb((oi + a - 4) & 127, (tx + 31) & 31)];
    #pragma unroll
    for (int t = T0; t < 4; ++t) {
      acc[t][a * 4 + 0] += cf[t][4] * m.x;
      acc[t][a * 4 + 1] += cf[t][4] * m.y;
      acc[t][a * 4 + 2] += cf[t][4] * m.z;
      acc[t][a * 4 + 3] += cf[t][4] * m.w;
    }
  }
  // ---- rot90 (k=1): out[i][j] = src[j][127-i] ----
  #pragma unroll
  for (int rb = 0; rb < 4; ++rb) {
    float4 m = l4[swb(oj + rb, 31 - ty)];
    // word w of block (31-ty) is col 124-4ty+w = 127-oi-a -> a = 3-w
    #pragma unroll
    for (int t = T0; t < 4; ++t) {
      acc[t][0 * 4 + rb] += cf[t][5] * m.w;
      acc[t][1 * 4 + rb] += cf[t][5] * m.z;
      acc[t][2 * 4 + rb] += cf[t][5] * m.y;
      acc[t][3 * 4 + rb] += cf[t][5] * m.x;
    }
  }
}

template<int P, int T0>
__device__ __forceinline__ void do_pass(const float* __restrict__ wsf, const float4* l4,
    const float* l1, int oi, int oj, int ty, int tx, float (&acc)[4][16])
{
  float cf[4][6];
  #pragma unroll
  for (int t = T0; t < 4; ++t) {
    #pragma unroll
    for (int k = 0; k < 6; ++k) cf[t][k] = wsf[WS_TAB + (P * 4 + t) * 6 + k];
  }
  gather_pass<T0>(l4, l1, oi, oj, ty, tx, cf, acc);
}

// amdgpu_waves_per_eu(4,4): pin occupancy to exactly one 1024-thread block
// per CU (4 waves/SIMD). Without it the allocator targeted the LDS-feasible
// 8 waves/SIMD -> 64-VGPR cap -> acc[4][16] spilled to scratch (~1.4 GB HBM
// traffic, 510us). 4 waves/SIMD gives a 128-VGPR budget; kernel needs ~110.
__global__ __launch_bounds__(1024)
__attribute__((amdgpu_waves_per_eu(4, 4)))
void main_kernel(const float* __restrict__ x,
    const float* __restrict__ wsf, float* __restrict__ out)
{
  __shared__ float lds[PLANE];   // 64 KB: one 128x128 plane, swizzled
  float4* l4 = (float4*)lds;
  int bx = blockIdx.x;
  int b = bx / NCH, c = bx % NCH;
  int tid = threadIdx.x;
  int ty = tid >> 5, tx = tid & 31;
  int oi = ty << 2, oj = tx << 2;

  // stage s = BN(x) into LDS
  float sc = wsf[WS_SCALE + c], sh = wsf[WS_SHIFT + c];
  const float4* x4 = (const float4*)x + (size_t)bx * 4096;
  #pragma unroll
  for (int r = 0; r < 4; ++r) {
    float4 v = x4[(oi + r) * 32 + tx];
    float4 sv;
    sv.x = v.x * sc + sh; sv.y = v.y * sc + sh;
    sv.z = v.z * sc + sh; sv.w = v.w * sc + sh;
    l4[swb(oi + r, tx)] = sv;
  }

  float acc[4][16];
  #pragma unroll
  for (int t = 0; t < 4; ++t) {
    float cst = wsf[WS_CONST + t];
    #pragma unroll
    for (int k = 0; k < 16; ++k) acc[t][k] = cst;
  }
  __syncthreads();

  float4* out4 = (float4*)out;
  const size_t pbase = (size_t)b * 192 + c;

  // pass 1: src = s, targets s2..s5
  do_pass<0, 0>(wsf, l4, lds, oi, oj, ty, tx, acc);
  #pragma unroll
  for (int r = 0; r < 4; ++r) {
    float4 v; v.x = acc[0][r*4+0]; v.y = acc[0][r*4+1]; v.z = acc[0][r*4+2]; v.w = acc[0][r*4+3];
    out4[(pbase + 0 * NCH) * 4096 + (oi + r) * 32 + tx] = v;
  }
  __syncthreads();
  #pragma unroll
  for (int r = 0; r < 4; ++r) {
    float4 v; v.x = acc[0][r*4+0]; v.y = acc[0][r*4+1]; v.z = acc[0][r*4+2]; v.w = acc[0][r*4+3];
    l4[swb(oi + r, tx)] = v;
  }
  __syncthreads();

  // pass 2: src = s2, targets s3..s5
  do_pass<1, 1>(wsf, l4, lds, oi, oj, ty, tx, acc);
  #pragma unroll
  for (int r = 0; r < 4; ++r) {
    float4 v; v.x = acc[1][r*4+0]; v.y = acc[1][r*4+1]; v.z = acc[1][r*4+2]; v.w = acc[1][r*4+3];
    out4[(pbase + 1 * NCH) * 4096 + (oi + r) * 32 + tx] = v;
  }
  __syncthreads();
  #pragma unroll
  for (int r = 0; r < 4; ++r) {
    float4 v; v.x = acc[1][r*4+0]; v.y = acc[1][r*4+1]; v.z = acc[1][r*4+2]; v.w = acc[1][r*4+3];
    l4[swb(oi + r, tx)] = v;
  }
  __syncthreads();

  // pass 3: src = s3, targets s4..s5
  do_pass<2, 2>(wsf, l4, lds, oi, oj, ty, tx, acc);
  #pragma unroll
  for (int r = 0; r < 4; ++r) {
    float4 v; v.x = acc[2][r*4+0]; v.y = acc[2][r*4+1]; v.z = acc[2][r*4+2]; v.w = acc[2][r*4+3];
    out4[(pbase + 2 * NCH) * 4096 + (oi + r) * 32 + tx] = v;
  }
  __syncthreads();
  #pragma unroll
  for (int r = 0; r < 4; ++r) {
    float4 v; v.x = acc[2][r*4+0]; v.y = acc[2][r*4+1]; v.z = acc[2][r*4+2]; v.w = acc[2][r*4+3];
    l4[swb(oi + r, tx)] = v;
  }
  __syncthreads();

  // pass 4: src = s4, target s5
  do_pass<3, 3>(wsf, l4, lds, oi, oj, ty, tx, acc);
  #pragma unroll
  for (int r = 0; r < 4; ++r) {
    float4 v; v.x = acc[3][r*4+0]; v.y = acc[3][r*4+1]; v.z = acc[3][r*4+2]; v.w = acc[3][r*4+3];
    out4[(pbase + 3 * NCH) * 4096 + (oi + r) * 32 + tx] = v;
  }
}

extern "C" void kernel_launch(void* const* d_in, const int* in_sizes, int n_in,
                              void* d_out, int out_size, void* d_ws, size_t ws_size,
                              hipStream_t stream) {
  (void)in_sizes; (void)n_in; (void)out_size; (void)ws_size;
  const float* x     = (const float*)d_in[0];
  const float* gamma = (const float*)d_in[1];
  const float* beta  = (const float*)d_in[2];
  const float* a_red = (const float*)d_in[4];   // reference uses alphas_reduce
  float* ws  = (float*)d_ws;
  float* out = (float*)d_out;

  stats_kernel<<<NPLANES, 256, 0, stream>>>(x, ws);
  prep_kernel<<<1, 64, 0, stream>>>(gamma, beta, a_red, ws);
  main_kernel<<<NPLANES, 1024, 0, stream>>>(x, ws, out);
}

// Round 5
// 384.833 us; speedup vs baseline: 1.3790x; 1.3169x over previous
//
#include <hip/hip_runtime.h>
#include <math.h>

#define NCH 48
#define NB 16
#define PLANE 16384
#define NPLANES 768

// d_ws float layout
#define WS_PSUM  0      // 768 partial sums (per b,c plane)
#define WS_PSQ   768    // 768 partial sumsq
#define WS_SCALE 1536   // 48
#define WS_SHIFT 1584   // 48
#define WS_TAB   1632   // [src 4][tgt 4][6 coefs]
#define WS_CONST 1728   // [4]

// compile-time for: guarantees every array index is a literal constant in IR
// (rule #20: runtime-indexed per-thread arrays go to scratch; #pragma unroll
// alone did NOT prevent that here -> 1.4 GB scratch traffic, 505us).
template<int I> struct ic { static constexpr int v = I; };
template<int S, int E, typename F>
__device__ __forceinline__ void sfor(F&& f) {
  if constexpr (S < E) { f(ic<S>{}); sfor<S + 1, E>(f); }
}

// ---------------- stage A: per-plane partial sums ----------------
__global__ __launch_bounds__(256) void stats_kernel(const float* __restrict__ x,
                                                    float* __restrict__ ws) {
  int p = blockIdx.x;      // plane = b*48+c
  int t = threadIdx.x;
  const float4* x4 = (const float4*)x + (size_t)p * 4096;
  float s = 0.f, q = 0.f;
  #pragma unroll
  for (int k = 0; k < 16; ++k) {          // 256 thr * 16 = 4096 float4 = full plane
    float4 v = x4[k * 256 + t];
    s += v.x + v.y + v.z + v.w;
    q += v.x * v.x + v.y * v.y + v.z * v.z + v.w * v.w;
  }
  #pragma unroll
  for (int off = 32; off > 0; off >>= 1) {
    s += __shfl_xor(s, off, 64);
    q += __shfl_xor(q, off, 64);
  }
  __shared__ float red[8];
  int wid = t >> 6, lane = t & 63;
  if (lane == 0) { red[wid] = s; red[4 + wid] = q; }
  __syncthreads();
  if (t == 0) {
    ws[WS_PSUM + p] = red[0] + red[1] + red[2] + red[3];
    ws[WS_PSQ  + p] = red[4] + red[5] + red[6] + red[7];
  }
}

// ---------------- stage B: finalize BN params + weight table ----------------
__global__ void prep_kernel(const float* __restrict__ gamma, const float* __restrict__ beta,
                            const float* __restrict__ alphas, float* __restrict__ ws) {
  int t = threadIdx.x;
  if (t < NCH) {
    float s = 0.f, q = 0.f;
    for (int b = 0; b < NB; ++b) {
      s += ws[WS_PSUM + b * NCH + t];
      q += ws[WS_PSQ  + b * NCH + t];
    }
    const float inv = 1.0f / ((float)NB * PLANE);
    float mean = s * inv;
    float var  = q * inv - mean * mean;
    float sc = gamma[t] * rsqrtf(var + 1e-5f);
    ws[WS_SCALE + t] = sc;
    ws[WS_SHIFT + t] = beta[t] - mean * sc;
  }
  if (t == 0) {
    float w[14][7];
    for (int r = 0; r < 14; ++r) {
      float m = -1e30f;
      for (int k = 0; k < 7; ++k) m = fmaxf(m, alphas[r * 7 + k]);
      float sum = 0.f;
      for (int k = 0; k < 7; ++k) { float e = expf(alphas[r * 7 + k] - m); w[r][k] = e; sum += e; }
      float is = 1.0f / sum;
      for (int k = 0; k < 7; ++k) w[r][k] *= is;
    }
    for (int i = 0; i < 96; ++i) ws[WS_TAB + i] = 0.f;
    for (int i = 0; i < 4;  ++i) ws[WS_CONST + i] = 0.f;
    // weight-row -> (source p, target tg): s2=rows{0,1}; s3={2,3 | s2:4};
    // s4={5,6 | s2:7 | s3:8}; s5={9,10 | s2:11 | s3:12 | s4:13}
    const int map[14][2] = {
      {0,0},{0,0},
      {0,1},{0,1},{1,1},
      {0,2},{0,2},{1,2},{2,2},
      {0,3},{0,3},{1,3},{2,3},{3,3}
    };
    for (int r = 0; r < 14; ++r) {
      int p = map[r][0], tg = map[r][1];
      float* cf = ws + WS_TAB + (p * 4 + tg) * 6;
      cf[0] += w[r][0] - w[r][2];       // identity  (w0*h - w2*h)
      cf[1] += w[r][1] * (1.0f / 9.0f); // blur (fold /9)
      cf[2] += w[r][3];                 // fliplr
      cf[3] += w[r][4];                 // flipud
      cf[4] += w[r][5];                 // roll(+4,+4)
      cf[5] += w[r][6];                 // rot90
      ws[WS_CONST + tg] += w[r][2];     // constant w2*1
    }
  }
}

// ---------------- main fused kernel ----------------
// LDS swizzle: float4-block index for (row i, block bj): bj ^= (i>>2)&7.
__device__ __forceinline__ int swb(int i, int bj) {
  return (i << 5) + (bj ^ ((i >> 2) & 7));
}
__device__ __forceinline__ float ldsw(const float* l, int i, int j) {
  int bj = j >> 2;
  return l[(i << 7) + (((bj ^ ((i >> 2) & 7)) << 2) | (j & 3))];
}

template<int T0>
__device__ __forceinline__ void gather_pass(const float4* l4, const float* l1,
    int oi, int oj, int ty, int tx, const float (&cf)[4][6], float (&acc)[4][16])
{
  // ---- identity + box blur (6 rows x 6 cols, reflect borders) ----
  int cLo = (tx == 0)  ? 1   : oj - 1;
  int cHi = (tx == 31) ? 126 : oj + 4;
  float hs[3][4];
  sfor<0, 6>([&](auto RC) {
    constexpr int r = RC.v;
    int ri = oi - 1 + r;
    ri = (ri < 0) ? 1 : ((ri > 127) ? 126 : ri);
    float4 mid = l4[swb(ri, tx)];
    float lo = ldsw(l1, ri, cLo);
    float hi = ldsw(l1, ri, cHi);
    if constexpr (r >= 1 && r <= 4) {
      constexpr int a = r - 1;
      sfor<T0, 4>([&](auto TC) {
        constexpr int t = TC.v;
        acc[t][a * 4 + 0] += cf[t][0] * mid.x;
        acc[t][a * 4 + 1] += cf[t][0] * mid.y;
        acc[t][a * 4 + 2] += cf[t][0] * mid.z;
        acc[t][a * 4 + 3] += cf[t][0] * mid.w;
      });
    }
    hs[r % 3][0] = lo    + mid.x + mid.y;
    hs[r % 3][1] = mid.x + mid.y + mid.z;
    hs[r % 3][2] = mid.y + mid.z + mid.w;
    hs[r % 3][3] = mid.z + mid.w + hi;
    if constexpr (r >= 2) {
      constexpr int a = r - 2;
      sfor<0, 4>([&](auto QC) {
        constexpr int bq = QC.v;
        float bb = hs[0][bq] + hs[1][bq] + hs[2][bq];
        sfor<T0, 4>([&](auto TC) {
          constexpr int t = TC.v;
          acc[t][a * 4 + bq] += cf[t][1] * bb;
        });
      });
    }
  });
  // ---- fliplr: out[i][j] = src[i][127-j] ----
  sfor<0, 4>([&](auto AC) {
    constexpr int a = AC.v;
    float4 m = l4[swb(oi + a, 31 - tx)];
    sfor<T0, 4>([&](auto TC) {
      constexpr int t = TC.v;
      acc[t][a * 4 + 0] += cf[t][2] * m.w;
      acc[t][a * 4 + 1] += cf[t][2] * m.z;
      acc[t][a * 4 + 2] += cf[t][2] * m.y;
      acc[t][a * 4 + 3] += cf[t][2] * m.x;
    });
  });
  // ---- flipud: out[i][j] = src[127-i][j] ----
  sfor<0, 4>([&](auto AC) {
    constexpr int a = AC.v;
    float4 m = l4[swb(127 - oi - a, tx)];
    sfor<T0, 4>([&](auto TC) {
      constexpr int t = TC.v;
      acc[t][a * 4 + 0] += cf[t][3] * m.x;
      acc[t][a * 4 + 1] += cf[t][3] * m.y;
      acc[t][a * 4 + 2] += cf[t][3] * m.z;
      acc[t][a * 4 + 3] += cf[t][3] * m.w;
    });
  });
  // ---- roll(+4,+4): out[i][j] = src[(i-4)&127][(j-4)&127] ----
  sfor<0, 4>([&](auto AC) {
    constexpr int a = AC.v;
    float4 m = l4[swb((oi + a - 4) & 127, (tx + 31) & 31)];
    sfor<T0, 4>([&](auto TC) {
      constexpr int t = TC.v;
      acc[t][a * 4 + 0] += cf[t][4] * m.x;
      acc[t][a * 4 + 1] += cf[t][4] * m.y;
      acc[t][a * 4 + 2] += cf[t][4] * m.z;
      acc[t][a * 4 + 3] += cf[t][4] * m.w;
    });
  });
  // ---- rot90 (k=1): out[i][j] = src[j][127-i] ----
  sfor<0, 4>([&](auto RB) {
    constexpr int rb = RB.v;
    float4 m = l4[swb(oj + rb, 31 - ty)];
    // word w of block (31-ty) is col 124-4ty+w = 127-oi-a -> a = 3-w
    sfor<T0, 4>([&](auto TC) {
      constexpr int t = TC.v;
      acc[t][0 * 4 + rb] += cf[t][5] * m.w;
      acc[t][1 * 4 + rb] += cf[t][5] * m.z;
      acc[t][2 * 4 + rb] += cf[t][5] * m.y;
      acc[t][3 * 4 + rb] += cf[t][5] * m.x;
    });
  });
}

template<int P, int T0>
__device__ __forceinline__ void do_pass(const float* __restrict__ wsf, const float4* l4,
    const float* l1, int oi, int oj, int ty, int tx, float (&acc)[4][16])
{
  float cf[4][6];
  sfor<T0, 4>([&](auto TC) {
    constexpr int t = TC.v;
    sfor<0, 6>([&](auto KC) {
      constexpr int k = KC.v;
      cf[t][k] = wsf[WS_TAB + (P * 4 + t) * 6 + k];
    });
  });
  gather_pass<T0>(l4, l1, oi, oj, ty, tx, cf, acc);
}

// Write state P's acc to global / stash into LDS — constexpr indices only.
#define WRITE_STATE(P)                                                          \
  sfor<0, 4>([&](auto RC) {                                                     \
    constexpr int r = RC.v;                                                     \
    float4 v; v.x = acc[P][r*4+0]; v.y = acc[P][r*4+1];                         \
    v.z = acc[P][r*4+2]; v.w = acc[P][r*4+3];                                   \
    out4[(pbase + P * NCH) * 4096 + (oi + r) * 32 + tx] = v;                    \
  })
#define STASH_STATE(P)                                                          \
  sfor<0, 4>([&](auto RC) {                                                     \
    constexpr int r = RC.v;                                                     \
    float4 v; v.x = acc[P][r*4+0]; v.y = acc[P][r*4+1];                         \
    v.z = acc[P][r*4+2]; v.w = acc[P][r*4+3];                                   \
    l4[swb(oi + r, tx)] = v;                                                    \
  })

// LDS padded to 96 KB: forces 1 block/CU (160/96) -> 4 waves/EU occupancy
// target -> 128-VGPR budget, matching waves_per_eu(4,4). With the default
// 64 KB the LDS-feasible 8 waves/EU capped VGPRs at 64 (< acc's 64).
#define LDS_PAD 24576   // floats = 96 KB

__global__ __launch_bounds__(1024)
__attribute__((amdgpu_waves_per_eu(4, 4)))
void main_kernel(const float* __restrict__ x,
    const float* __restrict__ wsf, float* __restrict__ out)
{
  __shared__ float lds[LDS_PAD];   // first 64 KB used: one 128x128 plane, swizzled
  float4* l4 = (float4*)lds;
  int bx = blockIdx.x;
  int b = bx / NCH, c = bx % NCH;
  int tid = threadIdx.x;
  int ty = tid >> 5, tx = tid & 31;
  int oi = ty << 2, oj = tx << 2;

  // stage s = BN(x) into LDS
  float sc = wsf[WS_SCALE + c], sh = wsf[WS_SHIFT + c];
  const float4* x4 = (const float4*)x + (size_t)bx * 4096;
  sfor<0, 4>([&](auto RC) {
    constexpr int r = RC.v;
    float4 v = x4[(oi + r) * 32 + tx];
    float4 sv;
    sv.x = v.x * sc + sh; sv.y = v.y * sc + sh;
    sv.z = v.z * sc + sh; sv.w = v.w * sc + sh;
    l4[swb(oi + r, tx)] = sv;
  });

  float acc[4][16];
  sfor<0, 4>([&](auto TC) {
    constexpr int t = TC.v;
    float cst = wsf[WS_CONST + t];
    sfor<0, 16>([&](auto KC) { acc[t][KC.v] = cst; });
  });
  __syncthreads();

  float4* out4 = (float4*)out;
  const size_t pbase = (size_t)b * 192 + c;

  // pass 1: src = s, targets s2..s5
  do_pass<0, 0>(wsf, l4, lds, oi, oj, ty, tx, acc);
  WRITE_STATE(0);
  __syncthreads();
  STASH_STATE(0);
  __syncthreads();

  // pass 2: src = s2, targets s3..s5
  do_pass<1, 1>(wsf, l4, lds, oi, oj, ty, tx, acc);
  WRITE_STATE(1);
  __syncthreads();
  STASH_STATE(1);
  __syncthreads();

  // pass 3: src = s3, targets s4..s5
  do_pass<2, 2>(wsf, l4, lds, oi, oj, ty, tx, acc);
  WRITE_STATE(2);
  __syncthreads();
  STASH_STATE(2);
  __syncthreads();

  // pass 4: src = s4, target s5
  do_pass<3, 3>(wsf, l4, lds, oi, oj, ty, tx, acc);
  WRITE_STATE(3);
}

extern "C" void kernel_launch(void* const* d_in, const int* in_sizes, int n_in,
                              void* d_out, int out_size, void* d_ws, size_t ws_size,
                              hipStream_t stream) {
  (void)in_sizes; (void)n_in; (void)out_size; (void)ws_size;
  const float* x     = (const float*)d_in[0];
  const float* gamma = (const float*)d_in[1];
  const float* beta  = (const float*)d_in[2];
  const float* a_red = (const float*)d_in[4];   // reference uses alphas_reduce
  float* ws  = (float*)d_ws;
  float* out = (float*)d_out;

  stats_kernel<<<NPLANES, 256, 0, stream>>>(x, ws);
  prep_kernel<<<1, 64, 0, stream>>>(gamma, beta, a_red, ws);
  main_kernel<<<NPLANES, 1024, 0, stream>>>(x, ws, out);
}